// Round 1
// baseline (185.518 us; speedup 1.0000x reference)
//
#include <hip/hip_runtime.h>

#define D_DIM 1024
#define C_CLS 64
#define N_SUP 4096
#define M_Q   8192
#define BM 32
#define BK 32

// K1: per support row n: rinv = 1/||gS[n]||; atomicAdd normalized row into W[tgt[n]][:]
__global__ __launch_bounds__(256) void k_accum_W(const float* __restrict__ gS,
                                                 const int* __restrict__ tgt,
                                                 float* __restrict__ W) {
    const int n = blockIdx.x;
    const int t = threadIdx.x;
    // 256 threads x float4 = 1024 floats (one row), fully coalesced
    const float4 v = reinterpret_cast<const float4*>(gS + (size_t)n * D_DIM)[t];
    float ss = v.x * v.x + v.y * v.y + v.z * v.z + v.w * v.w;
#pragma unroll
    for (int off = 32; off > 0; off >>= 1)
        ss += __shfl_xor(ss, off, 64);
    __shared__ float wsum[4];
    if ((t & 63) == 0) wsum[t >> 6] = ss;
    __syncthreads();
    const float total = wsum[0] + wsum[1] + wsum[2] + wsum[3];
    const float rinv = rsqrtf(fmaxf(total, 1e-24f));
    const int c = tgt[n];
    float* Wd = W + (size_t)c * D_DIM + t * 4;
    atomicAdd(Wd + 0, v.x * rinv);
    atomicAdd(Wd + 1, v.y * rinv);
    atomicAdd(Wd + 2, v.z * rinv);
    atomicAdd(Wd + 3, v.w * rinv);
}

// K2: out[m,c] = (1/||fX[m]||) * dot(fX[m], W[c]).  BM=32 rows x all 64 classes
// per block; K-loop in BK=32 chunks; k-major LDS tiles so compute reads are
// vector (float2 A / float4 B) and broadcast-heavy (conflict-free).
__global__ __launch_bounds__(256) void k_out(const float* __restrict__ fX,
                                             const float* __restrict__ W,
                                             float* __restrict__ out) {
    __shared__ float As[BK][BM];       // As[k][m]
    __shared__ float Bs[BK][C_CLS];    // Bs[k][c]
    __shared__ float rowSS[8][BM];
    __shared__ float rinvS[BM];

    const int t = threadIdx.x;
    const int m_base = blockIdx.x * BM;

    // A load: row ra = t&31, col group ga = t>>5 (8 groups x 4 floats)
    const int ra = t & 31, ga = t >> 5;
    // B load: row rb = t&63, col group gb = t>>6 (4 groups x 8 floats)
    const int rb = t & 63, gb = t >> 6;
    // compute mapping: 2 m-rows x 4 classes per thread
    const int tx = t & 15, ty = t >> 4;

    float acc00 = 0.f, acc01 = 0.f, acc02 = 0.f, acc03 = 0.f;
    float acc10 = 0.f, acc11 = 0.f, acc12 = 0.f, acc13 = 0.f;
    float ssA = 0.f;

    const float* Ap = fX + (size_t)(m_base + ra) * D_DIM + ga * 4;
    const float* Bp = W + (size_t)rb * D_DIM + gb * 8;

    for (int kb = 0; kb < D_DIM; kb += BK) {
        const float4 a4 = *reinterpret_cast<const float4*>(Ap + kb);
        const float4 b0 = *reinterpret_cast<const float4*>(Bp + kb);
        const float4 b1 = *reinterpret_cast<const float4*>(Bp + kb + 4);
        ssA += a4.x * a4.x + a4.y * a4.y + a4.z * a4.z + a4.w * a4.w;
        __syncthreads();   // previous chunk's compute done before overwrite
        As[ga * 4 + 0][ra] = a4.x;
        As[ga * 4 + 1][ra] = a4.y;
        As[ga * 4 + 2][ra] = a4.z;
        As[ga * 4 + 3][ra] = a4.w;
        Bs[gb * 8 + 0][rb] = b0.x;
        Bs[gb * 8 + 1][rb] = b0.y;
        Bs[gb * 8 + 2][rb] = b0.z;
        Bs[gb * 8 + 3][rb] = b0.w;
        Bs[gb * 8 + 4][rb] = b1.x;
        Bs[gb * 8 + 5][rb] = b1.y;
        Bs[gb * 8 + 6][rb] = b1.z;
        Bs[gb * 8 + 7][rb] = b1.w;
        __syncthreads();
#pragma unroll
        for (int k = 0; k < BK; ++k) {
            const float2 a = *reinterpret_cast<const float2*>(&As[k][ty * 2]);
            const float4 b = *reinterpret_cast<const float4*>(&Bs[k][tx * 4]);
            acc00 = fmaf(a.x, b.x, acc00);
            acc01 = fmaf(a.x, b.y, acc01);
            acc02 = fmaf(a.x, b.z, acc02);
            acc03 = fmaf(a.x, b.w, acc03);
            acc10 = fmaf(a.y, b.x, acc10);
            acc11 = fmaf(a.y, b.y, acc11);
            acc12 = fmaf(a.y, b.z, acc12);
            acc13 = fmaf(a.y, b.w, acc13);
        }
    }
    // reduce per-row sumsq of fX (each thread saw row ra's cols {ga*4..} over all chunks)
    rowSS[ga][ra] = ssA;
    __syncthreads();
    if (t < BM) {
        float s = 0.f;
#pragma unroll
        for (int g = 0; g < 8; ++g) s += rowSS[g][t];
        rinvS[t] = rsqrtf(fmaxf(s, 1e-24f));
    }
    __syncthreads();
    const float r0 = rinvS[ty * 2], r1 = rinvS[ty * 2 + 1];
    float4 o;
    o = make_float4(acc00 * r0, acc01 * r0, acc02 * r0, acc03 * r0);
    *reinterpret_cast<float4*>(out + (size_t)(m_base + ty * 2) * C_CLS + tx * 4) = o;
    o = make_float4(acc10 * r1, acc11 * r1, acc12 * r1, acc13 * r1);
    *reinterpret_cast<float4*>(out + (size_t)(m_base + ty * 2 + 1) * C_CLS + tx * 4) = o;
}

extern "C" void kernel_launch(void* const* d_in, const int* in_sizes, int n_in,
                              void* d_out, int out_size, void* d_ws, size_t ws_size,
                              hipStream_t stream) {
    const float* gS = (const float*)d_in[0];
    const float* fX = (const float*)d_in[1];
    const int* tgt = (const int*)d_in[2];
    float* W = (float*)d_ws;          // C_CLS x D_DIM fp32 = 256 KB scratch
    float* out = (float*)d_out;

    hipMemsetAsync(W, 0, (size_t)C_CLS * D_DIM * sizeof(float), stream);
    hipLaunchKernelGGL(k_accum_W, dim3(N_SUP), dim3(256), 0, stream, gS, tgt, W);
    hipLaunchKernelGGL(k_out, dim3(M_Q / BM), dim3(256), 0, stream, fX, W, out);
}

// Round 3
// 128.004 us; speedup vs baseline: 1.4493x; 1.4493x over previous
//
#include <hip/hip_runtime.h>
#include <hip/hip_bf16.h>

#define D_DIM 1024
#define C_CLS 64
#define N_SUP 4096
#define M_Q   8192

typedef __attribute__((ext_vector_type(8))) short short8;
typedef __attribute__((ext_vector_type(4))) float f32x4;

__device__ inline unsigned short f2bf(float x) {
    __hip_bfloat16 h = __float2bfloat16(x);
    return __builtin_bit_cast(unsigned short, h);
}

// ---------------- Pass A: rinv[n] = 1/||gS[n]|| ----------------
__global__ __launch_bounds__(256) void k_norms(const float* __restrict__ gS,
                                               float* __restrict__ rinv) {
    const int n = blockIdx.x;
    const int t = threadIdx.x;
    const float4 v = reinterpret_cast<const float4*>(gS + (size_t)n * D_DIM)[t];
    float ss = v.x * v.x + v.y * v.y + v.z * v.z + v.w * v.w;
#pragma unroll
    for (int off = 32; off > 0; off >>= 1)
        ss += __shfl_xor(ss, off, 64);
    __shared__ float ws[4];
    if ((t & 63) == 0) ws[t >> 6] = ss;
    __syncthreads();
    if (t == 0) {
        const float tot = ws[0] + ws[1] + ws[2] + ws[3];
        rinv[n] = rsqrtf(fmaxf(tot, 1e-24f));
    }
}

// ---------------- Pass B: W_bf[c][d] = sum_{n: tgt[n]==c} gS[n][d]*rinv[n] ----
// grid = 64 classes x 4 col-chunks of 256. No global atomics: per-block
// class-list in LDS, register accumulation, single bf16 write.
#define BD 256
__global__ __launch_bounds__(256) void k_classW(const float* __restrict__ gS,
                                                const int* __restrict__ tgt,
                                                const float* __restrict__ rinv,
                                                unsigned short* __restrict__ Wb) {
    const int c  = blockIdx.x >> 2;
    const int d0 = (blockIdx.x & 3) * BD;
    const int t  = threadIdx.x;

    __shared__ int   cnt;
    __shared__ int   lst[N_SUP];
    __shared__ float rvs[N_SUP];

    if (t == 0) cnt = 0;
    __syncthreads();
#pragma unroll
    for (int n = t; n < N_SUP; n += 256) {
        if (tgt[n] == c) {
            const int i = atomicAdd(&cnt, 1);   // LDS atomic
            lst[i] = n;
        }
    }
    __syncthreads();
    const int k = cnt;
    for (int i = t; i < k; i += 256) rvs[i] = rinv[lst[i]];
    __syncthreads();

    float acc = 0.f;
#pragma unroll 8
    for (int i = 0; i < k; ++i) {
        const float v = gS[(size_t)lst[i] * D_DIM + d0 + t];
        acc = fmaf(v, rvs[i], acc);
    }
    Wb[(size_t)c * D_DIM + d0 + t] = f2bf(acc);
}

// ---------------- K2: out[m,c] = rinvF[m] * sum_k fX[m,k]*W[c,k]  (bf16 MFMA)
// 1 wave per block, 16 rows; grid 8192/16 = 512. A staged fp32->bf16 in LDS
// (row stride 136 bf16 = 272 B -> conflict-free b128 frag reads); B-frags
// straight from L2-resident bf16 W. Row sumsq computed during staging.
#define KC 128
#define LDA 136
__global__ __launch_bounds__(64) void k_out_mfma(const float* __restrict__ fX,
                                                 const unsigned short* __restrict__ Wb,
                                                 float* __restrict__ out) {
    __shared__ unsigned short A[16 * LDA];   // 4352 B
    __shared__ float rowss[16 * 32];         // 2 KB
    __shared__ float rinvR[16];

    const int t  = threadIdx.x;
    const int m0 = blockIdx.x * 16;
    const float* Ab = fX + (size_t)m0 * D_DIM;

    f32x4 acc[4] = {};
    float ssr[8] = {};

    // prologue: load chunk 0 (16 rows x 128 cols fp32 = 512 float4, 8/thread)
    float4 ld[8];
#pragma unroll
    for (int j = 0; j < 8; ++j) {
        const int f = t + 64 * j, r = f >> 5, c4 = f & 31;
        ld[j] = reinterpret_cast<const float4*>(Ab + (size_t)r * D_DIM)[c4];
    }

    for (int kc = 0; kc < 8; ++kc) {
        // convert + sumsq + LDS write (chunk kc)
#pragma unroll
        for (int j = 0; j < 8; ++j) {
            const int f = t + 64 * j, r = f >> 5, c4 = f & 31;
            const float4 v = ld[j];
            ssr[j] += v.x * v.x + v.y * v.y + v.z * v.z + v.w * v.w;
            ushort4 b;
            b.x = f2bf(v.x); b.y = f2bf(v.y); b.z = f2bf(v.z); b.w = f2bf(v.w);
            *reinterpret_cast<ushort4*>(&A[r * LDA + c4 * 4]) = b;
        }
        // prefetch next chunk's globals (overlap with MFMA below)
        if (kc < 7) {
#pragma unroll
            for (int j = 0; j < 8; ++j) {
                const int f = t + 64 * j, r = f >> 5, c4 = f & 31;
                ld[j] = reinterpret_cast<const float4*>(Ab + (size_t)r * D_DIM + (kc + 1) * KC)[c4];
            }
        }
        __syncthreads();
#pragma unroll
        for (int ks = 0; ks < 4; ++ks) {
            // A-frag: row = t&15, k = (t>>4)*8 + ks*32 (within chunk)
            const short8 a = *reinterpret_cast<const short8*>(
                &A[(t & 15) * LDA + (t >> 4) * 8 + ks * 32]);
#pragma unroll
            for (int ct = 0; ct < 4; ++ct) {
                // B-frag: col c = ct*16 + (t&15), 8 contiguous k at kc*128+ks*32+(t>>4)*8
                const short8 b = *reinterpret_cast<const short8*>(
                    Wb + (size_t)(ct * 16 + (t & 15)) * D_DIM + kc * KC + ks * 32 + (t >> 4) * 8);
                acc[ct] = __builtin_amdgcn_mfma_f32_16x16x32_bf16(a, b, acc[ct], 0, 0, 0);
            }
        }
        __syncthreads();
    }

    // per-row sumsq reduction: thread t holds rows 2j + (t>>5)
#pragma unroll
    for (int j = 0; j < 8; ++j)
        rowss[(2 * j + (t >> 5)) * 32 + (t & 31)] = ssr[j];
    __syncthreads();
    if (t < 16) {
        float s = 0.f;
#pragma unroll
        for (int i = 0; i < 32; ++i) s += rowss[t * 32 + i];
        rinvR[t] = rsqrtf(fmaxf(s, 1e-24f));
    }
    __syncthreads();

    // epilogue: C/D layout col = lane&15, row = (lane>>4)*4 + reg
    const int col = t & 15;
#pragma unroll
    for (int r = 0; r < 4; ++r) {
        const int row = (t >> 4) * 4 + r;
        const float rv = rinvR[row];
#pragma unroll
        for (int ct = 0; ct < 4; ++ct)
            out[(size_t)(m0 + row) * C_CLS + ct * 16 + col] = acc[ct][r] * rv;
    }
}

extern "C" void kernel_launch(void* const* d_in, const int* in_sizes, int n_in,
                              void* d_out, int out_size, void* d_ws, size_t ws_size,
                              hipStream_t stream) {
    const float* gS  = (const float*)d_in[0];
    const float* fX  = (const float*)d_in[1];
    const int*   tgt = (const int*)d_in[2];
    float* out = (float*)d_out;

    float* rinv = (float*)d_ws;                                  // 16 KB
    unsigned short* Wb = (unsigned short*)((char*)d_ws + 16384); // 128 KB bf16

    hipLaunchKernelGGL(k_norms,    dim3(N_SUP),     dim3(256), 0, stream, gS, rinv);
    hipLaunchKernelGGL(k_classW,   dim3(C_CLS * 4), dim3(256), 0, stream, gS, tgt, rinv, Wb);
    hipLaunchKernelGGL(k_out_mfma, dim3(M_Q / 16),  dim3(64),  0, stream, fX, Wb, out);
}

// Round 4
// 106.801 us; speedup vs baseline: 1.7370x; 1.1985x over previous
//
#include <hip/hip_runtime.h>
#include <hip/hip_bf16.h>

#define D_DIM 1024
#define C_CLS 64
#define N_SUP 4096
#define M_Q   8192

typedef __attribute__((ext_vector_type(8))) short short8;
typedef __attribute__((ext_vector_type(4))) float f32x4;

__device__ inline unsigned short f2bf(float x) {
    __hip_bfloat16 h = __float2bfloat16(x);
    return __builtin_bit_cast(unsigned short, h);
}

// ---------------- Pass A: rinv[n] = 1/||gS[n]||. One wave per row, no LDS,
// no syncthreads. grid 1024 x 256thr = 16 waves/CU.
__global__ __launch_bounds__(256) void k_norms(const float* __restrict__ gS,
                                               float* __restrict__ rinv) {
    const int t = threadIdx.x;
    const int l = t & 63;
    const int n = blockIdx.x * 4 + (t >> 6);
    const float4* R = reinterpret_cast<const float4*>(gS + (size_t)n * D_DIM);
    float ss = 0.f;
#pragma unroll
    for (int q = 0; q < 4; ++q) {
        const float4 v = R[l + 64 * q];
        ss += v.x * v.x + v.y * v.y + v.z * v.z + v.w * v.w;
    }
#pragma unroll
    for (int off = 32; off > 0; off >>= 1)
        ss += __shfl_xor(ss, off, 64);
    if (l == 0) rinv[n] = rsqrtf(fmaxf(ss, 1e-24f));
}

// ---------------- Pass B: W_bf[c][d] = sum_{n: tgt[n]==c} gS[n][d]*rinv[n]
// grid = 64 classes x 16 col-chunks of 64 = 1024 blocks (4/CU, 16 waves/CU).
// 4 waves each take every 4th class member; LDS combine. No global atomics.
#define LMAX 512
__global__ __launch_bounds__(256) void k_classW(const float* __restrict__ gS,
                                                const int* __restrict__ tgt,
                                                const float* __restrict__ rinv,
                                                unsigned short* __restrict__ Wb) {
    const int c   = blockIdx.x >> 4;
    const int d0  = (blockIdx.x & 15) * 64;
    const int t   = threadIdx.x;
    const int h   = t >> 6;      // wave id 0..3
    const int col = t & 63;

    __shared__ int   cnt;
    __shared__ int   lst[LMAX];
    __shared__ float rvs[LMAX];
    __shared__ float PP[4][64];

    if (t == 0) cnt = 0;
    __syncthreads();
    for (int n = t; n < N_SUP; n += 256) {
        if (tgt[n] == c) {
            const int i = atomicAdd(&cnt, 1);   // LDS atomic
            if (i < LMAX) lst[i] = n;
        }
    }
    __syncthreads();
    const int k = min(cnt, LMAX);
    for (int i = t; i < k; i += 256) rvs[i] = rinv[lst[i]];
    __syncthreads();

    float acc = 0.f;
#pragma unroll 4
    for (int i = h; i < k; i += 4)
        acc = fmaf(gS[(size_t)lst[i] * D_DIM + d0 + col], rvs[i], acc);

    PP[h][col] = acc;
    __syncthreads();
    if (t < 64)
        Wb[(size_t)c * D_DIM + d0 + t] =
            f2bf(PP[0][t] + PP[1][t] + PP[2][t] + PP[3][t]);
}

// ---------------- K2: out[m,c] = rinvF[m] * sum_k fX[m,k]*W[c,k] (bf16 MFMA)
// 256thr = 4 waves per block; block owns 16 rows; wave w owns k-quarter
// [w*256,(w+1)*256). Private per-wave LDS A-buffers -> NO barrier in K-loop
// (same-wave lgkmcnt only); chunk-1 globals stay in flight across chunk-0
// MFMAs. Cross-wave f32 partial reduce at the end. grid 512 = 8 waves/CU.
#define LDA 136
#define KQ  256
__global__ __launch_bounds__(256) void k_out_mfma(const float* __restrict__ fX,
                                                  const unsigned short* __restrict__ Wb,
                                                  float* __restrict__ out) {
    __shared__ unsigned short A[4][2][16 * LDA];  // 34.8 KB
    __shared__ float P[4][16][64];                // 16 KB partial C
    __shared__ float SS[4][16][32];               // 8 KB partial sumsq
    __shared__ float rinvR[16];

    const int t  = threadIdx.x;
    const int w  = t >> 6, l = t & 63;
    const int m0 = blockIdx.x * 16;
    const float* Ab = fX + (size_t)m0 * D_DIM + w * KQ;

    // issue both chunks' global loads up-front (16 float4 in flight)
    float4 ld0[8], ld1[8];
#pragma unroll
    for (int j = 0; j < 8; ++j) {
        const int f = l + 64 * j, r = f >> 5, c4 = f & 31;
        ld0[j] = reinterpret_cast<const float4*>(Ab + (size_t)r * D_DIM)[c4];
        ld1[j] = reinterpret_cast<const float4*>(Ab + (size_t)r * D_DIM + 128)[c4];
    }

    f32x4 acc[4] = {};
    float ssr[8];
#pragma unroll
    for (int j = 0; j < 8; ++j) ssr[j] = 0.f;

#pragma unroll
    for (int ch = 0; ch < 2; ++ch) {
        // convert chunk -> private LDS buffer (same-wave visibility only)
#pragma unroll
        for (int j = 0; j < 8; ++j) {
            const int f = l + 64 * j, r = f >> 5, c4 = f & 31;
            const float4 v = (ch == 0) ? ld0[j] : ld1[j];
            ssr[j] += v.x * v.x + v.y * v.y + v.z * v.z + v.w * v.w;
            ushort4 b;
            b.x = f2bf(v.x); b.y = f2bf(v.y); b.z = f2bf(v.z); b.w = f2bf(v.w);
            *reinterpret_cast<ushort4*>(&A[w][ch][r * LDA + c4 * 4]) = b;
        }
#pragma unroll
        for (int ks = 0; ks < 4; ++ks) {
            const short8 a = *reinterpret_cast<const short8*>(
                &A[w][ch][(l & 15) * LDA + (l >> 4) * 8 + ks * 32]);
#pragma unroll
            for (int ct = 0; ct < 4; ++ct) {
                const short8 b = *reinterpret_cast<const short8*>(
                    Wb + (size_t)(ct * 16 + (l & 15)) * D_DIM + w * KQ + ch * 128 +
                    ks * 32 + (l >> 4) * 8);
                acc[ct] = __builtin_amdgcn_mfma_f32_16x16x32_bf16(a, b, acc[ct], 0, 0, 0);
            }
        }
    }

    // stash per-wave partials
#pragma unroll
    for (int ct = 0; ct < 4; ++ct)
#pragma unroll
        for (int r = 0; r < 4; ++r)
            P[w][(l >> 4) * 4 + r][ct * 16 + (l & 15)] = acc[ct][r];
#pragma unroll
    for (int j = 0; j < 8; ++j)
        SS[w][(l >> 5) + 2 * j][l & 31] = ssr[j];
    __syncthreads();

    // reduce sumsq: 64 threads -> per (wave,row); then 16 threads -> rinv
    if (t < 64) {
        const int w2 = t >> 4, row = t & 15;
        float s = 0.f;
#pragma unroll
        for (int i = 0; i < 32; ++i) s += SS[w2][row][i];
        SS[w2][row][0] = s;
    }
    __syncthreads();
    if (t < 16)
        rinvR[t] = rsqrtf(fmaxf(SS[0][t][0] + SS[1][t][0] + SS[2][t][0] + SS[3][t][0], 1e-24f));
    __syncthreads();

    // final: each thread sums 4 partials for 4 outputs, scales, stores float4
    const int row = t >> 4, cb = (t & 15) * 4;
    const f32x4 p0 = *reinterpret_cast<const f32x4*>(&P[0][row][cb]);
    const f32x4 p1 = *reinterpret_cast<const f32x4*>(&P[1][row][cb]);
    const f32x4 p2 = *reinterpret_cast<const f32x4*>(&P[2][row][cb]);
    const f32x4 p3 = *reinterpret_cast<const f32x4*>(&P[3][row][cb]);
    const float rv = rinvR[row];
    f32x4 o = (p0 + p1 + p2 + p3) * rv;
    *reinterpret_cast<f32x4*>(out + (size_t)(m0 + row) * C_CLS + cb) = o;
}

extern "C" void kernel_launch(void* const* d_in, const int* in_sizes, int n_in,
                              void* d_out, int out_size, void* d_ws, size_t ws_size,
                              hipStream_t stream) {
    const float* gS  = (const float*)d_in[0];
    const float* fX  = (const float*)d_in[1];
    const int*   tgt = (const int*)d_in[2];
    float* out = (float*)d_out;

    float* rinv = (float*)d_ws;                                  // 16 KB
    unsigned short* Wb = (unsigned short*)((char*)d_ws + 16384); // 128 KB bf16

    hipLaunchKernelGGL(k_norms,    dim3(N_SUP / 4), dim3(256), 0, stream, gS, rinv);
    hipLaunchKernelGGL(k_classW,   dim3(C_CLS * 16), dim3(256), 0, stream, gS, tgt, rinv, Wb);
    hipLaunchKernelGGL(k_out_mfma, dim3(M_Q / 16),  dim3(256), 0, stream, fX, Wb, out);
}